// Round 19
// baseline (132.568 us; speedup 1.0000x reference)
//
#include <hip/hip_runtime.h>
#include <math.h>

#define IN_CH 256
#define OUT_CH 64
#define BK_LOG 8
#define BK_NODES 256            // nodes per bucket (391 buckets @ N=100K)
#define NBK_CAP 1024            // max buckets (N <= 262144)
#define BK_CAP 6144             // padded edge capacity per bucket (mean 4096 + 32 sigma)
#define DIST_TILE 2048          // edges per distribute block (782 blocks @ E=1.6M)

typedef unsigned short ushort_t;
typedef unsigned int uint_t;
typedef __attribute__((ext_vector_type(8))) short bf16x8;
typedef __attribute__((ext_vector_type(4))) float f32x4;

__device__ __forceinline__ float b2f(uint_t u) {  // low 16 bits = bf16
    union { uint_t i; float f; } c; c.i = u << 16; return c.f;
}
__device__ __forceinline__ float b2fh(uint_t u) { // high 16 bits = bf16
    union { uint_t i; float f; } c; c.i = u & 0xFFFF0000u; return c.f;
}
__device__ __forceinline__ uint_t f2b(float f) {  // round-to-nearest-even
    union { float f; uint_t i; } c; c.f = f;
    return (c.i + 0x7FFFu + ((c.i >> 16) & 1u)) >> 16;
}

// ---------------------------------------------------------------------------
__global__ void k_zero(int* __restrict__ p, int n) {
    int i = blockIdx.x * blockDim.x + threadIdx.x;
    if (i < n) p[i] = 0;
}

// ---------------------------------------------------------------------------
// Bucket-sort edges into padded per-bucket regions: packed[b*BK_CAP ...].
// Per-block LDS histogram, one global reservation per bucket per block.
// bucketCur[b] ends up = bucket edge count (regions start at b*BK_CAP).
// ---------------------------------------------------------------------------
__global__ __launch_bounds__(256) void k_distribute(
    const int* __restrict__ src, const int* __restrict__ dst,
    int* __restrict__ bucketCur, uint_t* __restrict__ packed,
    int E, int nbk)
{
    __shared__ int hist[NBK_CAP];
    __shared__ int base[NBK_CAP];
    const int tid = threadIdx.x;
    const int t0 = blockIdx.x * DIST_TILE;
    const int t1 = min(E, t0 + DIST_TILE);

    for (int b = tid; b < nbk; b += 256) hist[b] = 0;
    __syncthreads();
    for (int i = t0 + tid; i < t1; i += 256) atomicAdd(&hist[dst[i] >> BK_LOG], 1);
    __syncthreads();
    for (int b = tid; b < nbk; b += 256)
        base[b] = hist[b] ? (b * BK_CAP + atomicAdd(&bucketCur[b], hist[b])) : 0;
    __syncthreads();
    for (int i = t0 + tid; i < t1; i += 256) {
        const int d = dst[i];
        const int p = atomicAdd(&base[d >> BK_LOG], 1);
        packed[p] = (uint_t)src[i] | ((uint_t)(d & (BK_NODES - 1)) << 24);
    }
}

// ---------------------------------------------------------------------------
// One block per bucket: LDS histogram of local dst -> per-node {start,end}
// + dinv, then LDS-cursor counting sort to exact dst order: list[p] = src.
// ---------------------------------------------------------------------------
__global__ __launch_bounds__(256) void k_sortbucket(
    const uint_t* __restrict__ packed, const int* __restrict__ bucketCur,
    int2* __restrict__ offsend, int* __restrict__ list, float* __restrict__ dinv,
    int N)
{
    __shared__ int hist[BK_NODES];
    __shared__ int scan[BK_NODES];
    const int tid = threadIdx.x;
    const int b = blockIdx.x;
    const int bo = b * BK_CAP;
    const int eo = bo + bucketCur[b];

    hist[tid] = 0;
    __syncthreads();
    for (int i = bo + tid; i < eo; i += 256)
        atomicAdd(&hist[packed[i] >> 24], 1);
    __syncthreads();

    int v = hist[tid];
    scan[tid] = v;
    __syncthreads();
    for (int off = 1; off < BK_NODES; off <<= 1) {
        int u = (tid >= off) ? scan[tid - off] : 0;
        __syncthreads();
        scan[tid] += u;
        __syncthreads();
    }
    const int excl = scan[tid] - v;

    const int node = b * BK_NODES + tid;
    if (node < N) {
        offsend[node] = make_int2(bo + excl, bo + excl + v);
        dinv[node] = rsqrtf((float)v + 1.0f);   // +1 self loop
    }

    hist[tid] = bo + excl;  // reuse as cursor
    __syncthreads();
    for (int i = bo + tid; i < eo; i += 256) {
        const uint_t pv = packed[i];
        const int p = atomicAdd(&hist[pv >> 24], 1);
        list[p] = (int)(pv & 0xFFFFFFu);
    }
}

// ---------------------------------------------------------------------------
// Wt[col][k] = bf16(W[k][col])  (64 x 256, 32 KB). Coalesced ushort writes.
// ---------------------------------------------------------------------------
__global__ __launch_bounds__(256) void k_prepW(const float* __restrict__ W,
                                               ushort_t* __restrict__ Wt) {
    const int j = blockIdx.x * 256 + threadIdx.x;   // 0..16383
    const int col = j >> 8, k = j & 255;
    Wt[j] = (ushort_t)f2b(W[k * OUT_CH + col]);
}

// ---------------------------------------------------------------------------
// g2(bf16) = (x @ W) * dinv[row] via MFMA 16x16x32 bf16.
// 256 thr = 4 waves x 16 rows = 64 rows/block. Wt staged in 32 KB LDS with
// XOR swizzle (byte ^= (col&7)<<4). D layout: row=(l>>4)*4+reg, col=l&15.
// ---------------------------------------------------------------------------
__global__ __launch_bounds__(256) void k_gemm_mfma(
    const float* __restrict__ x, const ushort_t* __restrict__ Wt,
    const float* __restrict__ dinv, ushort_t* __restrict__ g2, int N)
{
    __shared__ ushort_t Ws[OUT_CH * IN_CH];  // 32 KB, XOR-swizzled
    const int tid = threadIdx.x;
    for (int i = tid * 8; i < OUT_CH * IN_CH; i += 256 * 8) {
        const int col = i >> 8;
        const uint_t byte = (uint_t)(i * 2) ^ ((uint_t)(col & 7) << 4);
        *(uint4*)((char*)Ws + byte) = *(const uint4*)&Wt[i];
    }
    __syncthreads();

    const int lane = tid & 63;
    const int l16 = lane & 15;
    const int lq = lane >> 4;
    const int rowbase = blockIdx.x * 64 + (tid >> 6) * 16;

    const int arow = min(rowbase + l16, N - 1);
    const float* __restrict__ xr = x + (size_t)arow * IN_CH + lq * 8;

    f32x4 acc[4];
#pragma unroll
    for (int c = 0; c < 4; ++c) acc[c] = (f32x4){0.f, 0.f, 0.f, 0.f};

    for (int k0 = 0; k0 < IN_CH; k0 += 32) {
        const float4 xa = *(const float4*)&xr[k0];
        const float4 xb = *(const float4*)&xr[k0 + 4];
        bf16x8 a;
        a[0] = (short)f2b(xa.x); a[1] = (short)f2b(xa.y);
        a[2] = (short)f2b(xa.z); a[3] = (short)f2b(xa.w);
        a[4] = (short)f2b(xb.x); a[5] = (short)f2b(xb.y);
        a[6] = (short)f2b(xb.z); a[7] = (short)f2b(xb.w);
        const int kk = (k0 + lq * 8) * 2;  // byte offset of k within a row
#pragma unroll
        for (int c = 0; c < 4; ++c) {
            const int col = c * 16 + l16;
            const uint_t byte = (uint_t)(col * 512 + kk) ^ ((uint_t)(col & 7) << 4);
            const bf16x8 bfrag = *(const bf16x8*)((const char*)Ws + byte);
            acc[c] = __builtin_amdgcn_mfma_f32_16x16x32_bf16(a, bfrag, acc[c], 0, 0, 0);
        }
    }

#pragma unroll
    for (int r = 0; r < 4; ++r) {
        const int row = rowbase + lq * 4 + r;
        if (row < N) {
            const float dv = dinv[row];
            const size_t o = (size_t)row * OUT_CH;
            g2[o +  0 + l16] = (ushort_t)f2b(acc[0][r] * dv);
            g2[o + 16 + l16] = (ushort_t)f2b(acc[1][r] * dv);
            g2[o + 32 + l16] = (ushort_t)f2b(acc[2][r] * dv);
            g2[o + 48 + l16] = (ushort_t)f2b(acc[3][r] * dv);
        }
    }
}

// ---------------------------------------------------------------------------
// One wave per TWO nodes, 8-lane channel groups (lane l8 owns 8 channels =
// one dwordx4; group q = lane>>3 owns edge positions ==q mod 8). Both nodes'
// gathers issue in one fused loop (wave-uniform predicates) -> 32 edges in
// flight; node boundaries no longer drain the memory pipe.
// ---------------------------------------------------------------------------
__global__ void k_aggregate(const int2* __restrict__ offsend,
                            const int* __restrict__ list,
                            const ushort_t* __restrict__ g2, const float* __restrict__ b,
                            float* __restrict__ out, int N)
{
    const int lane = threadIdx.x & 63;
    const int l8 = lane & 7;
    const int q = lane >> 3;
    int wid = (blockIdx.x * blockDim.x + threadIdx.x) >> 6;
    const int nw = (gridDim.x * blockDim.x) >> 6;
    const float4 bcA = *(const float4*)&b[l8 * 8];
    const float4 bcB = *(const float4*)&b[l8 * 8 + 4];

    for (int i0 = wid * 2; i0 < N; i0 += nw * 2) {
        const int i1 = i0 + 1;
        const int2 se0 = offsend[i0];
        const int2 se1 = (i1 < N) ? offsend[i1] : make_int2(0, 0);

        float A0=0.f,A1=0.f,A2=0.f,A3=0.f,A4=0.f,A5=0.f,A6=0.f,A7=0.f;
        float B0=0.f,B1=0.f,B2=0.f,B3=0.f,B4=0.f,B5=0.f,B6=0.f,B7=0.f;

        int e0 = se0.x + q;
        int e1 = se1.x + q;
        // fused main loop: both nodes' gathers issue together (32 edges in flight)
        while ((e0 + 8 < se0.y) || (e1 + 8 < se1.y)) {
            if (e0 + 8 < se0.y) {
                const int s0 = list[e0];
                const int s1 = list[e0 + 8];
                const uint4 v0 = *(const uint4*)&g2[(size_t)s0 * OUT_CH + l8 * 8];
                const uint4 v1 = *(const uint4*)&g2[(size_t)s1 * OUT_CH + l8 * 8];
                A0 += b2f(v0.x & 0xFFFFu) + b2f(v1.x & 0xFFFFu);
                A1 += b2fh(v0.x) + b2fh(v1.x);
                A2 += b2f(v0.y & 0xFFFFu) + b2f(v1.y & 0xFFFFu);
                A3 += b2fh(v0.y) + b2fh(v1.y);
                A4 += b2f(v0.z & 0xFFFFu) + b2f(v1.z & 0xFFFFu);
                A5 += b2fh(v0.z) + b2fh(v1.z);
                A6 += b2f(v0.w & 0xFFFFu) + b2f(v1.w & 0xFFFFu);
                A7 += b2fh(v0.w) + b2fh(v1.w);
                e0 += 16;
            }
            if (e1 + 8 < se1.y) {
                const int s0 = list[e1];
                const int s1 = list[e1 + 8];
                const uint4 v0 = *(const uint4*)&g2[(size_t)s0 * OUT_CH + l8 * 8];
                const uint4 v1 = *(const uint4*)&g2[(size_t)s1 * OUT_CH + l8 * 8];
                B0 += b2f(v0.x & 0xFFFFu) + b2f(v1.x & 0xFFFFu);
                B1 += b2fh(v0.x) + b2fh(v1.x);
                B2 += b2f(v0.y & 0xFFFFu) + b2f(v1.y & 0xFFFFu);
                B3 += b2fh(v0.y) + b2fh(v1.y);
                B4 += b2f(v0.z & 0xFFFFu) + b2f(v1.z & 0xFFFFu);
                B5 += b2fh(v0.z) + b2fh(v1.z);
                B6 += b2f(v0.w & 0xFFFFu) + b2f(v1.w & 0xFFFFu);
                B7 += b2fh(v0.w) + b2fh(v1.w);
                e1 += 16;
            }
        }
        if (e0 < se0.y) {
            const int s = list[e0];
            const uint4 v = *(const uint4*)&g2[(size_t)s * OUT_CH + l8 * 8];
            A0 += b2f(v.x & 0xFFFFu); A1 += b2fh(v.x);
            A2 += b2f(v.y & 0xFFFFu); A3 += b2fh(v.y);
            A4 += b2f(v.z & 0xFFFFu); A5 += b2fh(v.z);
            A6 += b2f(v.w & 0xFFFFu); A7 += b2fh(v.w);
        }
        if (e1 < se1.y) {
            const int s = list[e1];
            const uint4 v = *(const uint4*)&g2[(size_t)s * OUT_CH + l8 * 8];
            B0 += b2f(v.x & 0xFFFFu); B1 += b2fh(v.x);
            B2 += b2f(v.y & 0xFFFFu); B3 += b2fh(v.y);
            B4 += b2f(v.z & 0xFFFFu); B5 += b2fh(v.z);
            B6 += b2f(v.w & 0xFFFFu); B7 += b2fh(v.w);
        }

        // ---- epilogue node i0 ----
        {
#pragma unroll
            for (int off = 8; off <= 32; off <<= 1) {
                A0 += __shfl_xor(A0, off); A1 += __shfl_xor(A1, off);
                A2 += __shfl_xor(A2, off); A3 += __shfl_xor(A3, off);
                A4 += __shfl_xor(A4, off); A5 += __shfl_xor(A5, off);
                A6 += __shfl_xor(A6, off); A7 += __shfl_xor(A7, off);
            }
            const uint4 sv = *(const uint4*)&g2[(size_t)i0 * OUT_CH + l8 * 8];
            A0 += b2f(sv.x & 0xFFFFu); A1 += b2fh(sv.x);
            A2 += b2f(sv.y & 0xFFFFu); A3 += b2fh(sv.y);
            A4 += b2f(sv.z & 0xFFFFu); A5 += b2fh(sv.z);
            A6 += b2f(sv.w & 0xFFFFu); A7 += b2fh(sv.w);

            const float dinv = rsqrtf((float)(se0.y - se0.x) + 1.0f);
            const float z0 = A0 * dinv + bcA.x;
            const float z1 = A1 * dinv + bcA.y;
            const float z2 = A2 * dinv + bcA.z;
            const float z3 = A3 * dinv + bcA.w;
            const float z4 = A4 * dinv + bcB.x;
            const float z5 = A5 * dinv + bcB.y;
            const float z6 = A6 * dinv + bcB.z;
            const float z7 = A7 * dinv + bcB.w;

            float m = fmaxf(fmaxf(fmaxf(z0, z1), fmaxf(z2, z3)),
                            fmaxf(fmaxf(z4, z5), fmaxf(z6, z7)));
#pragma unroll
            for (int off = 1; off < 8; off <<= 1) m = fmaxf(m, __shfl_xor(m, off));
            float s = __expf(z0-m)+__expf(z1-m)+__expf(z2-m)+__expf(z3-m)
                    + __expf(z4-m)+__expf(z5-m)+__expf(z6-m)+__expf(z7-m);
#pragma unroll
            for (int off = 1; off < 8; off <<= 1) s += __shfl_xor(s, off);
            const float ls = m + __logf(s);

            if (q == 0) {
                float* o = &out[(size_t)i0 * OUT_CH + l8 * 8];
                *(float4*)o       = make_float4(z0-ls, z1-ls, z2-ls, z3-ls);
                *(float4*)(o + 4) = make_float4(z4-ls, z5-ls, z6-ls, z7-ls);
            }
        }
        // ---- epilogue node i1 ----
        if (i1 < N) {
#pragma unroll
            for (int off = 8; off <= 32; off <<= 1) {
                B0 += __shfl_xor(B0, off); B1 += __shfl_xor(B1, off);
                B2 += __shfl_xor(B2, off); B3 += __shfl_xor(B3, off);
                B4 += __shfl_xor(B4, off); B5 += __shfl_xor(B5, off);
                B6 += __shfl_xor(B6, off); B7 += __shfl_xor(B7, off);
            }
            const uint4 sv = *(const uint4*)&g2[(size_t)i1 * OUT_CH + l8 * 8];
            B0 += b2f(sv.x & 0xFFFFu); B1 += b2fh(sv.x);
            B2 += b2f(sv.y & 0xFFFFu); B3 += b2fh(sv.y);
            B4 += b2f(sv.z & 0xFFFFu); B5 += b2fh(sv.z);
            B6 += b2f(sv.w & 0xFFFFu); B7 += b2fh(sv.w);

            const float dinv = rsqrtf((float)(se1.y - se1.x) + 1.0f);
            const float z0 = B0 * dinv + bcA.x;
            const float z1 = B1 * dinv + bcA.y;
            const float z2 = B2 * dinv + bcA.z;
            const float z3 = B3 * dinv + bcA.w;
            const float z4 = B4 * dinv + bcB.x;
            const float z5 = B5 * dinv + bcB.y;
            const float z6 = B6 * dinv + bcB.z;
            const float z7 = B7 * dinv + bcB.w;

            float m = fmaxf(fmaxf(fmaxf(z0, z1), fmaxf(z2, z3)),
                            fmaxf(fmaxf(z4, z5), fmaxf(z6, z7)));
#pragma unroll
            for (int off = 1; off < 8; off <<= 1) m = fmaxf(m, __shfl_xor(m, off));
            float s = __expf(z0-m)+__expf(z1-m)+__expf(z2-m)+__expf(z3-m)
                    + __expf(z4-m)+__expf(z5-m)+__expf(z6-m)+__expf(z7-m);
#pragma unroll
            for (int off = 1; off < 8; off <<= 1) s += __shfl_xor(s, off);
            const float ls = m + __logf(s);

            if (q == 0) {
                float* o = &out[(size_t)i1 * OUT_CH + l8 * 8];
                *(float4*)o       = make_float4(z0-ls, z1-ls, z2-ls, z3-ls);
                *(float4*)(o + 4) = make_float4(z4-ls, z5-ls, z6-ls, z7-ls);
            }
        }
    }
}

// ---------------------------------------------------------------------------
extern "C" void kernel_launch(void* const* d_in, const int* in_sizes, int n_in,
                              void* d_out, int out_size, void* d_ws, size_t ws_size,
                              hipStream_t stream) {
    const float* x  = (const float*)d_in[0];
    const int*   ei = (const int*)d_in[1];
    const float* W  = (const float*)d_in[2];
    const float* b  = (const float*)d_in[3];
    float* out = (float*)d_out;

    const int N = in_sizes[0] / IN_CH;  // 100000
    const int E = in_sizes[1] / 2;      // 1600000
    const int* src = ei;
    const int* dst = ei + E;

    const int nbk = (N + BK_NODES - 1) >> BK_LOG;          // 391
    const int ndist = (E + DIST_TILE - 1) / DIST_TILE;     // 782

    // ws: bucketCur[1024] | Wt[16384 bf16] | packed[nbk*BK_CAP] |
    //     list[nbk*BK_CAP] | offsend[N int2] | dinv[N] | g2[N*64 bf16] (~33 MB)
    char* p = (char*)d_ws;
    auto alloc = [&](size_t bytes) { char* q = p; p += (bytes + 255) & ~(size_t)255; return q; };
    int*      bucketCur = (int*)alloc(NBK_CAP * 4);
    ushort_t* Wt        = (ushort_t*)alloc((size_t)OUT_CH * IN_CH * 2);
    uint_t*   packed    = (uint_t*)alloc((size_t)nbk * BK_CAP * 4);
    int*      list      = (int*)alloc((size_t)nbk * BK_CAP * 4);
    int2*     offsend   = (int2*)alloc((size_t)N * 8);
    float*    dinv      = (float*)alloc((size_t)N * 4);
    ushort_t* g2        = (ushort_t*)alloc((size_t)N * OUT_CH * 2);

    k_zero      <<<(nbk + 255) / 256, 256, 0, stream>>>(bucketCur, nbk);
    k_prepW     <<<(OUT_CH * IN_CH) / 256, 256, 0, stream>>>(W, Wt);
    k_distribute<<<ndist, 256, 0, stream>>>(src, dst, bucketCur, packed, E, nbk);
    k_sortbucket<<<nbk, 256, 0, stream>>>(packed, bucketCur, offsend, list, dinv, N);
    k_gemm_mfma <<<(N + 63) / 64, 256, 0, stream>>>(x, Wt, dinv, g2, N);
    k_aggregate <<<4096, 256, 0, stream>>>(offsend, list, g2, b, out, N);
}

// Round 20
// 127.229 us; speedup vs baseline: 1.0420x; 1.0420x over previous
//
#include <hip/hip_runtime.h>
#include <math.h>

#define IN_CH 256
#define OUT_CH 64
#define BK_LOG 8
#define BK_NODES 256            // nodes per bucket (391 buckets @ N=100K)
#define NBK_CAP 1024            // max buckets (N <= 262144)
#define BK_CAP 6144             // padded edge capacity per bucket (mean 4096 + 32 sigma)
#define DIST_TILE 2048          // edges per distribute block (782 blocks @ E=1.6M)

typedef unsigned short ushort_t;
typedef unsigned int uint_t;
typedef __attribute__((ext_vector_type(8))) short bf16x8;
typedef __attribute__((ext_vector_type(4))) float f32x4;

__device__ __forceinline__ float b2f(uint_t u) {  // low 16 bits = bf16
    union { uint_t i; float f; } c; c.i = u << 16; return c.f;
}
__device__ __forceinline__ float b2fh(uint_t u) { // high 16 bits = bf16
    union { uint_t i; float f; } c; c.i = u & 0xFFFF0000u; return c.f;
}
__device__ __forceinline__ uint_t f2b(float f) {  // round-to-nearest-even
    union { float f; uint_t i; } c; c.f = f;
    return (c.i + 0x7FFFu + ((c.i >> 16) & 1u)) >> 16;
}

// ---------------------------------------------------------------------------
// Wt[col][k] = bf16(W[k][col]) (64 x 256, 32 KB); block 0 also zeroes
// bucketCur (folds the old k_zero launch into this one).
// ---------------------------------------------------------------------------
__global__ __launch_bounds__(256) void k_prepW(const float* __restrict__ W,
                                               ushort_t* __restrict__ Wt,
                                               int* __restrict__ bucketCur) {
    if (blockIdx.x == 0) {
        for (int i = threadIdx.x; i < NBK_CAP; i += 256) bucketCur[i] = 0;
    }
    const int j = blockIdx.x * 256 + threadIdx.x;   // 0..16383
    const int col = j >> 8, k = j & 255;
    Wt[j] = (ushort_t)f2b(W[k * OUT_CH + col]);
}

// ---------------------------------------------------------------------------
// Bucket-sort edges into padded per-bucket regions: packed[b*BK_CAP ...].
// Per-block LDS histogram, one global reservation per bucket per block.
// bucketCur[b] ends up = bucket edge count (regions start at b*BK_CAP).
// ---------------------------------------------------------------------------
__global__ __launch_bounds__(256) void k_distribute(
    const int* __restrict__ src, const int* __restrict__ dst,
    int* __restrict__ bucketCur, uint_t* __restrict__ packed,
    int E, int nbk)
{
    __shared__ int hist[NBK_CAP];
    __shared__ int base[NBK_CAP];
    const int tid = threadIdx.x;
    const int t0 = blockIdx.x * DIST_TILE;
    const int t1 = min(E, t0 + DIST_TILE);

    for (int b = tid; b < nbk; b += 256) hist[b] = 0;
    __syncthreads();
    for (int i = t0 + tid; i < t1; i += 256) atomicAdd(&hist[dst[i] >> BK_LOG], 1);
    __syncthreads();
    for (int b = tid; b < nbk; b += 256)
        base[b] = hist[b] ? (b * BK_CAP + atomicAdd(&bucketCur[b], hist[b])) : 0;
    __syncthreads();
    for (int i = t0 + tid; i < t1; i += 256) {
        const int d = dst[i];
        const int p = atomicAdd(&base[d >> BK_LOG], 1);
        packed[p] = (uint_t)src[i] | ((uint_t)(d & (BK_NODES - 1)) << 24);
    }
}

// ---------------------------------------------------------------------------
// One block per bucket: LDS histogram of local dst -> per-node {start,end}
// + dinv, then LDS-cursor counting sort to exact dst order: list[p] = src.
// ---------------------------------------------------------------------------
__global__ __launch_bounds__(256) void k_sortbucket(
    const uint_t* __restrict__ packed, const int* __restrict__ bucketCur,
    int2* __restrict__ offsend, int* __restrict__ list, float* __restrict__ dinv,
    int N)
{
    __shared__ int hist[BK_NODES];
    __shared__ int scan[BK_NODES];
    const int tid = threadIdx.x;
    const int b = blockIdx.x;
    const int bo = b * BK_CAP;
    const int eo = bo + bucketCur[b];

    hist[tid] = 0;
    __syncthreads();
    for (int i = bo + tid; i < eo; i += 256)
        atomicAdd(&hist[packed[i] >> 24], 1);
    __syncthreads();

    int v = hist[tid];
    scan[tid] = v;
    __syncthreads();
    for (int off = 1; off < BK_NODES; off <<= 1) {
        int u = (tid >= off) ? scan[tid - off] : 0;
        __syncthreads();
        scan[tid] += u;
        __syncthreads();
    }
    const int excl = scan[tid] - v;

    const int node = b * BK_NODES + tid;
    if (node < N) {
        offsend[node] = make_int2(bo + excl, bo + excl + v);
        dinv[node] = rsqrtf((float)v + 1.0f);   // +1 self loop
    }

    hist[tid] = bo + excl;  // reuse as cursor
    __syncthreads();
    for (int i = bo + tid; i < eo; i += 256) {
        const uint_t pv = packed[i];
        const int p = atomicAdd(&hist[pv >> 24], 1);
        list[p] = (int)(pv & 0xFFFFFFu);
    }
}

// ---------------------------------------------------------------------------
// g2(bf16) = (x @ W) * dinv[row] via MFMA 16x16x32 bf16.
// 512 thr = 8 waves x 16 rows = 128 rows/block (Wt staging amortized 2x).
// Wt staged in 32 KB LDS with XOR swizzle (byte ^= (col&7)<<4).
// D layout: row=(l>>4)*4+reg, col=l&15   [m89-verified].
// ---------------------------------------------------------------------------
__global__ __launch_bounds__(512) void k_gemm_mfma(
    const float* __restrict__ x, const ushort_t* __restrict__ Wt,
    const float* __restrict__ dinv, ushort_t* __restrict__ g2, int N)
{
    __shared__ ushort_t Ws[OUT_CH * IN_CH];  // 32 KB, XOR-swizzled
    const int tid = threadIdx.x;
    for (int i = tid * 8; i < OUT_CH * IN_CH; i += 512 * 8) {
        const int col = i >> 8;
        const uint_t byte = (uint_t)(i * 2) ^ ((uint_t)(col & 7) << 4);
        *(uint4*)((char*)Ws + byte) = *(const uint4*)&Wt[i];
    }
    __syncthreads();

    const int lane = tid & 63;
    const int l16 = lane & 15;
    const int lq = lane >> 4;
    const int rowbase = blockIdx.x * 128 + (tid >> 6) * 16;

    const int arow = min(rowbase + l16, N - 1);
    const float* __restrict__ xr = x + (size_t)arow * IN_CH + lq * 8;

    f32x4 acc[4];
#pragma unroll
    for (int c = 0; c < 4; ++c) acc[c] = (f32x4){0.f, 0.f, 0.f, 0.f};

    for (int k0 = 0; k0 < IN_CH; k0 += 32) {
        const float4 xa = *(const float4*)&xr[k0];
        const float4 xb = *(const float4*)&xr[k0 + 4];
        bf16x8 a;
        a[0] = (short)f2b(xa.x); a[1] = (short)f2b(xa.y);
        a[2] = (short)f2b(xa.z); a[3] = (short)f2b(xa.w);
        a[4] = (short)f2b(xb.x); a[5] = (short)f2b(xb.y);
        a[6] = (short)f2b(xb.z); a[7] = (short)f2b(xb.w);
        const int kk = (k0 + lq * 8) * 2;  // byte offset of k within a row
#pragma unroll
        for (int c = 0; c < 4; ++c) {
            const int col = c * 16 + l16;
            const uint_t byte = (uint_t)(col * 512 + kk) ^ ((uint_t)(col & 7) << 4);
            const bf16x8 bfrag = *(const bf16x8*)((const char*)Ws + byte);
            acc[c] = __builtin_amdgcn_mfma_f32_16x16x32_bf16(a, bfrag, acc[c], 0, 0, 0);
        }
    }

#pragma unroll
    for (int r = 0; r < 4; ++r) {
        const int row = rowbase + lq * 4 + r;
        if (row < N) {
            const float dv = dinv[row];
            const size_t o = (size_t)row * OUT_CH;
            g2[o +  0 + l16] = (ushort_t)f2b(acc[0][r] * dv);
            g2[o + 16 + l16] = (ushort_t)f2b(acc[1][r] * dv);
            g2[o + 32 + l16] = (ushort_t)f2b(acc[2][r] * dv);
            g2[o + 48 + l16] = (ushort_t)f2b(acc[3][r] * dv);
        }
    }
}

// ---------------------------------------------------------------------------
// One wave per node, 8-lane channel groups: lane l8=lane&7 owns channels
// 8*l8..+7 (one dwordx4 = 16 B); group q=lane>>3 owns edge positions ==q
// (mod 8). One wave instr covers 8 edge rows (1024 B). Unroll x2 -> 16 edges
// in flight. Merge shfl_xor(8,16,32); softmax over 8 lanes; q==0 writes.
// ---------------------------------------------------------------------------
__global__ void k_aggregate(const int2* __restrict__ offsend,
                            const int* __restrict__ list,
                            const ushort_t* __restrict__ g2, const float* __restrict__ b,
                            float* __restrict__ out, int N)
{
    const int lane = threadIdx.x & 63;
    const int l8 = lane & 7;          // channel octet: channels 8*l8 .. +7
    const int q = lane >> 3;          // edge-position group 0..7
    int wid = (blockIdx.x * blockDim.x + threadIdx.x) >> 6;
    const int nw = (gridDim.x * blockDim.x) >> 6;
    const float4 bcA = *(const float4*)&b[l8 * 8];
    const float4 bcB = *(const float4*)&b[l8 * 8 + 4];

    for (int i = wid; i < N; i += nw) {
        const int2 se = offsend[i];
        const int start = se.x, end = se.y;
        const int deg = end - start;
        float a0 = 0.f, a1 = 0.f, a2 = 0.f, a3 = 0.f;
        float a4 = 0.f, a5 = 0.f, a6 = 0.f, a7 = 0.f;

        int e = start + q;  // this group's positions: e, e+8, e+16, ...
        for (; e + 8 < end; e += 16) {   // 2 edges/group, 16/wave in flight
            const int s0 = list[e];
            const int s1 = list[e + 8];
            const uint4 v0 = *(const uint4*)&g2[(size_t)s0 * OUT_CH + l8 * 8];
            const uint4 v1 = *(const uint4*)&g2[(size_t)s1 * OUT_CH + l8 * 8];
            a0 += b2f(v0.x & 0xFFFFu) + b2f(v1.x & 0xFFFFu);
            a1 += b2fh(v0.x) + b2fh(v1.x);
            a2 += b2f(v0.y & 0xFFFFu) + b2f(v1.y & 0xFFFFu);
            a3 += b2fh(v0.y) + b2fh(v1.y);
            a4 += b2f(v0.z & 0xFFFFu) + b2f(v1.z & 0xFFFFu);
            a5 += b2fh(v0.z) + b2fh(v1.z);
            a6 += b2f(v0.w & 0xFFFFu) + b2f(v1.w & 0xFFFFu);
            a7 += b2fh(v0.w) + b2fh(v1.w);
        }
        if (e < end) {
            const int s = list[e];
            const uint4 v = *(const uint4*)&g2[(size_t)s * OUT_CH + l8 * 8];
            a0 += b2f(v.x & 0xFFFFu); a1 += b2fh(v.x);
            a2 += b2f(v.y & 0xFFFFu); a3 += b2fh(v.y);
            a4 += b2f(v.z & 0xFFFFu); a5 += b2fh(v.z);
            a6 += b2f(v.w & 0xFFFFu); a7 += b2fh(v.w);
        }

        // merge the 8 groups (reduce over q)
#pragma unroll
        for (int off = 8; off <= 32; off <<= 1) {
            a0 += __shfl_xor(a0, off); a1 += __shfl_xor(a1, off);
            a2 += __shfl_xor(a2, off); a3 += __shfl_xor(a3, off);
            a4 += __shfl_xor(a4, off); a5 += __shfl_xor(a5, off);
            a6 += __shfl_xor(a6, off); a7 += __shfl_xor(a7, off);
        }

        // self loop (post-reduce: each lane adds exactly once to its copy)
        const uint4 sv = *(const uint4*)&g2[(size_t)i * OUT_CH + l8 * 8];
        a0 += b2f(sv.x & 0xFFFFu); a1 += b2fh(sv.x);
        a2 += b2f(sv.y & 0xFFFFu); a3 += b2fh(sv.y);
        a4 += b2f(sv.z & 0xFFFFu); a5 += b2fh(sv.z);
        a6 += b2f(sv.w & 0xFFFFu); a7 += b2fh(sv.w);

        const float dinv = rsqrtf((float)deg + 1.0f);
        const float z0 = a0 * dinv + bcA.x;
        const float z1 = a1 * dinv + bcA.y;
        const float z2 = a2 * dinv + bcA.z;
        const float z3 = a3 * dinv + bcA.w;
        const float z4 = a4 * dinv + bcB.x;
        const float z5 = a5 * dinv + bcB.y;
        const float z6 = a6 * dinv + bcB.z;
        const float z7 = a7 * dinv + bcB.w;

        float m = fmaxf(fmaxf(fmaxf(z0, z1), fmaxf(z2, z3)),
                        fmaxf(fmaxf(z4, z5), fmaxf(z6, z7)));
#pragma unroll
        for (int off = 1; off < 8; off <<= 1) m = fmaxf(m, __shfl_xor(m, off));
        float s = __expf(z0 - m) + __expf(z1 - m) + __expf(z2 - m) + __expf(z3 - m)
                + __expf(z4 - m) + __expf(z5 - m) + __expf(z6 - m) + __expf(z7 - m);
#pragma unroll
        for (int off = 1; off < 8; off <<= 1) s += __shfl_xor(s, off);
        const float ls = m + __logf(s);

        if (q == 0) {
            float* o = &out[(size_t)i * OUT_CH + l8 * 8];
            *(float4*)o       = make_float4(z0 - ls, z1 - ls, z2 - ls, z3 - ls);
            *(float4*)(o + 4) = make_float4(z4 - ls, z5 - ls, z6 - ls, z7 - ls);
        }
    }
}

// ---------------------------------------------------------------------------
extern "C" void kernel_launch(void* const* d_in, const int* in_sizes, int n_in,
                              void* d_out, int out_size, void* d_ws, size_t ws_size,
                              hipStream_t stream) {
    const float* x  = (const float*)d_in[0];
    const int*   ei = (const int*)d_in[1];
    const float* W  = (const float*)d_in[2];
    const float* b  = (const float*)d_in[3];
    float* out = (float*)d_out;

    const int N = in_sizes[0] / IN_CH;  // 100000
    const int E = in_sizes[1] / 2;      // 1600000
    const int* src = ei;
    const int* dst = ei + E;

    const int nbk = (N + BK_NODES - 1) >> BK_LOG;          // 391
    const int ndist = (E + DIST_TILE - 1) / DIST_TILE;     // 782

    // ws: bucketCur[1024] | Wt[16384 bf16] | packed[nbk*BK_CAP] |
    //     list[nbk*BK_CAP] | offsend[N int2] | dinv[N] | g2[N*64 bf16] (~33 MB)
    char* p = (char*)d_ws;
    auto alloc = [&](size_t bytes) { char* q = p; p += (bytes + 255) & ~(size_t)255; return q; };
    int*      bucketCur = (int*)alloc(NBK_CAP * 4);
    ushort_t* Wt        = (ushort_t*)alloc((size_t)OUT_CH * IN_CH * 2);
    uint_t*   packed    = (uint_t*)alloc((size_t)nbk * BK_CAP * 4);
    int*      list      = (int*)alloc((size_t)nbk * BK_CAP * 4);
    int2*     offsend   = (int2*)alloc((size_t)N * 8);
    float*    dinv      = (float*)alloc((size_t)N * 4);
    ushort_t* g2        = (ushort_t*)alloc((size_t)N * OUT_CH * 2);

    k_prepW     <<<(OUT_CH * IN_CH) / 256, 256, 0, stream>>>(W, Wt, bucketCur);
    k_distribute<<<ndist, 256, 0, stream>>>(src, dst, bucketCur, packed, E, nbk);
    k_sortbucket<<<nbk, 256, 0, stream>>>(packed, bucketCur, offsend, list, dinv, N);
    k_gemm_mfma <<<(N + 127) / 128, 512, 0, stream>>>(x, Wt, dinv, g2, N);
    k_aggregate <<<4096, 256, 0, stream>>>(offsend, list, g2, b, out, N);
}